// Round 3
// baseline (438.405 us; speedup 1.0000x reference)
//
#include <hip/hip_runtime.h>
#include <hip/hip_bf16.h>

using bf16 = __hip_bfloat16;
typedef __attribute__((ext_vector_type(8))) short short8;
typedef __attribute__((ext_vector_type(16))) float f32x16;

#define NLAY 2
#define NN1 8
#define NN2 8
#define PP 1024
#define DD 768
#define MROWS (NN1*PP)   // 8192
#define BM 256
#define BN 256
#define BK 64
#define NKT (DD/BK)      // 12 K-tiles
#define NCT (MROWS/BN)   // 32 col tiles

// ---------------- normalize rows + convert to bf16 (both inputs fused) ----
__global__ __launch_bounds__(256) void normalize_kernel(
    const float* __restrict__ in0, const float* __restrict__ in1,
    bf16* __restrict__ out0, bf16* __restrict__ out1) {
  int row  = blockIdx.x * 4 + (threadIdx.x >> 6);
  int lane = threadIdx.x & 63;
  const int half = NLAY * MROWS;
  const float* src;
  bf16* dst;
  if (row < half) { src = in0 + (size_t)row * DD;          dst = out0 + (size_t)row * DD; }
  else            { src = in1 + (size_t)(row - half) * DD; dst = out1 + (size_t)(row - half) * DD; }
  float4 v[3];
  float ss = 0.f;
#pragma unroll
  for (int i = 0; i < 3; i++) {
    v[i] = *reinterpret_cast<const float4*>(src + lane * 4 + i * 256);
    ss += v[i].x * v[i].x + v[i].y * v[i].y + v[i].z * v[i].z + v[i].w * v[i].w;
  }
#pragma unroll
  for (int off = 1; off < 64; off <<= 1) ss += __shfl_xor(ss, off);
  float rn = rsqrtf(ss);
#pragma unroll
  for (int i = 0; i < 3; i++) {
    bf16 tmp[4];
    tmp[0] = __float2bfloat16(v[i].x * rn);
    tmp[1] = __float2bfloat16(v[i].y * rn);
    tmp[2] = __float2bfloat16(v[i].z * rn);
    tmp[3] = __float2bfloat16(v[i].w * rn);
    *reinterpret_cast<uint2*>(dst + lane * 4 + i * 256) =
        *reinterpret_cast<const uint2*>(tmp);
  }
}

// ---------------- 256x256 8-phase GEMM, 32x32x16 MFMA, fused row-max -------
// 512 threads = 8 waves: wr = wave>>2 (row half of wave rows), wc = wave&3
// (64-col stripe). Wave output 128x64. acc[4][2] f32x16 (a = qm*2+mt).
// LDS: As/Bs [2 dbuf][2 half][128*64] bf16 = 128 KiB, + red 4 KiB.
// Swizzle: 16B slot s of row r stored at s^(r&7); source pre-swizzled.

__device__ __forceinline__ short8 ld_frag(const bf16* h, int r, int slot) {
  return *reinterpret_cast<const short8*>(h + r * 64 + (((slot) ^ (r & 7)) << 3));
}

#define STAGE(Gbase, Lds) do {                                                  \
  _Pragma("unroll")                                                             \
  for (int i_ = 0; i_ < 2; i_++) {                                              \
    int u_ = i_ * 512 + t;                                                      \
    int r_ = u_ >> 3, s_ = u_ & 7;                                              \
    int sc_ = ((s_ ^ (r_ & 7)) << 3);                                           \
    __builtin_amdgcn_global_load_lds(                                           \
      (const __attribute__((address_space(1))) void*)((Gbase) + (size_t)r_ * DD + sc_), \
      (__attribute__((address_space(3))) void*)((Lds) + u_ * 8), 16, 0, 0);     \
  } } while (0)

#define VM2 asm volatile("s_waitcnt vmcnt(2)" ::: "memory")
#define VM0 asm volatile("s_waitcnt vmcnt(0)" ::: "memory")

#define LOAD_AF(buf, qm, kp)                                                    \
  _Pragma("unroll") for (int mt_ = 0; mt_ < 2; mt_++)                           \
  _Pragma("unroll") for (int j_ = 0; j_ < 2; j_++)                              \
    af_[mt_][j_] = ld_frag(&As[buf][qm][0], wr * 64 + mt_ * 32 + l31, ((kp) * 2 + j_) * 2 + hi);

#define LOAD_BF(buf, kp)                                                        \
  _Pragma("unroll") for (int n_ = 0; n_ < 2; n_++)                              \
  _Pragma("unroll") for (int j_ = 0; j_ < 2; j_++)                              \
    bf_[n_][j_] = ld_frag(&Bs[buf][hB][0], wcin * 64 + n_ * 32 + l31, ((kp) * 2 + j_) * 2 + hi);

#define MFMAS(qm)                                                               \
  __builtin_amdgcn_s_setprio(1);                                                \
  _Pragma("unroll") for (int j_ = 0; j_ < 2; j_++)                              \
  _Pragma("unroll") for (int mt_ = 0; mt_ < 2; mt_++)                           \
  _Pragma("unroll") for (int n_ = 0; n_ < 2; n_++)                              \
    acc[(qm) * 2 + mt_][n_] = __builtin_amdgcn_mfma_f32_32x32x16_bf16(          \
        af_[mt_][j_], bf_[n_][j_], acc[(qm) * 2 + mt_][n_], 0, 0, 0);           \
  __builtin_amdgcn_s_setprio(0);

#define PHASE_Q0(buf, kp, STG, VMC) do {                                        \
  LOAD_BF(buf, kp); LOAD_AF(buf, 0, kp);                                        \
  STG;                                                                          \
  __builtin_amdgcn_s_barrier();                                                 \
  asm volatile("s_waitcnt lgkmcnt(0)" ::: "memory");                            \
  MFMAS(0);                                                                     \
  VMC;                                                                          \
  __builtin_amdgcn_s_barrier();                                                 \
} while (0)

#define PHASE_Q1(buf, kp, STG, VMC) do {                                        \
  LOAD_AF(buf, 1, kp);                                                          \
  STG;                                                                          \
  __builtin_amdgcn_s_barrier();                                                 \
  asm volatile("s_waitcnt lgkmcnt(0)" ::: "memory");                            \
  MFMAS(1);                                                                     \
  VMC;                                                                          \
  __builtin_amdgcn_s_barrier();                                                 \
} while (0)

__global__ __launch_bounds__(512, 2) void gemm_max_kernel(
    const bf16* __restrict__ A, const bf16* __restrict__ Bm,
    float* __restrict__ partials) {
  __shared__ bf16 As[2][2][128 * 64];
  __shared__ bf16 Bs[2][2][128 * 64];
  __shared__ float red[4][256];

  // XCD-aware swizzle: xcd = id&7 owns (layer, 8-tiler band); within the
  // chunk, consecutive dispatch rounds cover 8 tiler x 4 tilec (~4.7MB in L2).
  const int id  = blockIdx.x;
  const int xcd = id & 7, p = id >> 3;
  const int l     = xcd >> 2;
  const int q     = p & 31, rnd = p >> 5;
  const int tiler = (xcd & 3) * 8 + (q & 7);
  const int tilec = rnd * 4 + (q >> 3);

  const bf16* Ab = A  + ((size_t)l * MROWS + (size_t)tiler * BM) * DD;
  const bf16* Bb = Bm + ((size_t)l * MROWS + (size_t)tilec * BN) * DD;

  const int t    = threadIdx.x;
  const int lane = t & 63;
  const int wave = t >> 6;
  const int wr   = wave >> 2;   // 0..1
  const int wc   = wave & 3;    // 0..3
  const int hB   = wc >> 1;     // B half
  const int wcin = wc & 1;      // 64-col stripe within half
  const int l31  = lane & 31;
  const int hi   = lane >> 5;

  f32x16 acc[4][2];
#pragma unroll
  for (int a = 0; a < 4; a++)
#pragma unroll
    for (int n = 0; n < 2; n++)
#pragma unroll
      for (int j = 0; j < 16; j++) acc[a][n][j] = 0.f;

  // prologue: tile0 (all 4 units) -> buf0, A0(tile1) -> buf1
  STAGE(Ab,                      &As[0][0][0]);
  STAGE(Ab + (size_t)128 * DD,   &As[0][1][0]);
  STAGE(Bb,                      &Bs[0][0][0]);
  STAGE(Bb + (size_t)128 * DD,   &Bs[0][1][0]);
  STAGE(Ab + BK,                 &As[1][0][0]);
  VM2;
  __builtin_amdgcn_s_barrier();

  for (int i = 0; i < NKT / 2; i++) {
    const int O = 2 * i + 1, NE = 2 * i + 2, NO = 2 * i + 3;
    short8 af_[2][2], bf_[2][2];
    // tile E=2i (buf0): phases (kp,qm) = (0,0),(0,1),(1,0),(1,1)
    PHASE_Q0(0, 0, STAGE(Bb + (size_t)O * BK,                    &Bs[1][0][0]), (void)0);
    PHASE_Q1(0, 0, STAGE(Bb + (size_t)128 * DD + (size_t)O * BK, &Bs[1][1][0]), (void)0);
    PHASE_Q0(0, 1, STAGE(Ab + (size_t)128 * DD + (size_t)O * BK, &As[1][1][0]), (void)0);
    PHASE_Q1(0, 1, if (NE < NKT) STAGE(Ab + (size_t)NE * BK, &As[0][0][0]),
             if (NE < NKT) { VM2; } else { VM0; });
    // tile O (buf1)
    PHASE_Q0(1, 0, if (NE < NKT) STAGE(Bb + (size_t)NE * BK, &Bs[0][0][0]), (void)0);
    PHASE_Q1(1, 0, if (NE < NKT) STAGE(Bb + (size_t)128 * DD + (size_t)NE * BK, &Bs[0][1][0]), (void)0);
    PHASE_Q0(1, 1, if (NE < NKT) STAGE(Ab + (size_t)128 * DD + (size_t)NE * BK, &As[0][1][0]), (void)0);
    PHASE_Q1(1, 1, if (NO < NKT) STAGE(Ab + (size_t)NO * BK, &As[1][0][0]), VM2);
  }

  // epilogue: per-row max over this block's 256 cols.
  // C/D (32x32): col = lane&31, row = (reg&3) + 8*(reg>>2) + 4*(lane>>5)
#pragma unroll
  for (int a = 0; a < 4; a++) {
#pragma unroll
    for (int j = 0; j < 16; j++) {
      float v = fmaxf(acc[a][0][j], acc[a][1][j]);
#pragma unroll
      for (int off = 1; off < 32; off <<= 1) v = fmaxf(v, __shfl_xor(v, off));
      if (l31 == 0) {
        int row = (a >> 1) * 128 + wr * 64 + (a & 1) * 32 + (j & 3) + 8 * (j >> 2) + 4 * hi;
        red[wc][row] = v;
      }
    }
  }
  __syncthreads();
  if (t < 256) {
    float v = fmaxf(fmaxf(red[0][t], red[1][t]), fmaxf(red[2][t], red[3][t]));
    partials[((size_t)l * MROWS + (size_t)tiler * BM + t) * NCT + tilec] = v;
  }
}

// ---------------- reduce: maxdot -> sp -> scores + spatch ------------------
__global__ __launch_bounds__(1024) void reduce_kernel(
    const float* __restrict__ partials, const float* __restrict__ mask,
    float* __restrict__ scores, float* __restrict__ spatch) {
  const int n1 = blockIdx.x;
  const int p  = threadIdx.x;
  const int row = n1 * PP + p;
  const float mk = mask[row];

  float sp[16];
  float ssum = 0.f;
#pragma unroll
  for (int l = 0; l < NLAY; l++) {
    const float* pr = partials + ((size_t)l * MROWS + row) * NCT;
#pragma unroll
    for (int n2 = 0; n2 < NN2; n2++) {
      float md = pr[n2 * 4];
#pragma unroll
      for (int tt = 1; tt < 4; tt++) md = fmaxf(md, pr[n2 * 4 + tt]);
      float d2 = fmaxf(2.f - 2.f * md, 1e-12f);
      float s  = 0.5f * sqrtf(d2) * mk;
      sp[l * 8 + n2] = s;
      ssum += s;
    }
  }
  spatch[row] = ssum * (1.f / 16.f);

  __shared__ float wred[16][16];
  __shared__ float sres[16];
  const int lane = p & 63;
  const int wave = p >> 6;
#pragma unroll
  for (int v = 0; v < 16; v++) {
    float x = sp[v];
#pragma unroll
    for (int off = 1; off < 64; off <<= 1) x = fmaxf(x, __shfl_xor(x, off));
    if (lane == 0) wred[wave][v] = x;
  }
  __syncthreads();
  if (p < 16) {
    float x = wred[0][p];
#pragma unroll
    for (int w = 1; w < 16; w++) x = fmaxf(x, wred[w][p]);
    sres[p] = x;
  }
  __syncthreads();
  if (p == 0) {
    float s = 0.f;
#pragma unroll
    for (int v = 0; v < 16; v++) s += sres[v];
    scores[n1] = s * (1.f / 16.f);
  }
}

// ---------------- bilinear 16x upsample [8,32,32] -> [8,512,512] -----------
__global__ __launch_bounds__(256) void upsample_kernel(
    const float* __restrict__ spatch, float* __restrict__ out) {
  int idx = blockIdx.x * 256 + threadIdx.x;
  if (idx >= NN1 * 512 * 512) return;
  int x = idx & 511;
  int y = (idx >> 9) & 511;
  int n = idx >> 18;
  float sx = (x + 0.5f) * 0.0625f - 0.5f;
  float sy = (y + 0.5f) * 0.0625f - 0.5f;
  int x0 = (int)floorf(sx); float wx = sx - (float)x0;
  int y0 = (int)floorf(sy); float wy = sy - (float)y0;
  int x1 = min(x0 + 1, 31); x0 = max(x0, 0);
  int y1 = min(y0 + 1, 31); y0 = max(y0, 0);
  const float* s = spatch + n * PP;
  float v00 = s[y0 * 32 + x0], v01 = s[y0 * 32 + x1];
  float v10 = s[y1 * 32 + x0], v11 = s[y1 * 32 + x1];
  float v = (1.f - wy) * ((1.f - wx) * v00 + wx * v01) +
            wy * ((1.f - wx) * v10 + wx * v11);
  out[idx] = v;
}

extern "C" void kernel_launch(void* const* d_in, const int* in_sizes, int n_in,
                              void* d_out, int out_size, void* d_ws, size_t ws_size,
                              hipStream_t stream) {
  const float* feats  = (const float*)d_in[0];
  const float* nfeats = (const float*)d_in[1];
  const float* mask   = (const float*)d_in[2];
  float* out = (float*)d_out;

  bf16* Abf = (bf16*)d_ws;                                     // 2*8192*768 bf16
  bf16* Bbf = Abf + (size_t)NLAY * MROWS * DD;                 // same size
  float* partials = (float*)(Bbf + (size_t)NLAY * MROWS * DD); // [2][8192][32] f32
  float* spatch   = partials + (size_t)NLAY * MROWS * NCT;     // [8][1024] f32

  normalize_kernel<<<(2 * NLAY * MROWS) / 4, 256, 0, stream>>>(feats, nfeats, Abf, Bbf);

  gemm_max_kernel<<<NCT * (MROWS / BM) * NLAY, 512, 0, stream>>>(Abf, Bbf, partials);

  reduce_kernel<<<NN1, 1024, 0, stream>>>(partials, mask, out, spatch);

  upsample_kernel<<<(NN1 * 512 * 512) / 256, 256, 0, stream>>>(spatch, out + 8);
}

// Round 5
// 360.250 us; speedup vs baseline: 1.2169x; 1.2169x over previous
//
#include <hip/hip_runtime.h>
#include <hip/hip_bf16.h>

using bf16 = __hip_bfloat16;
typedef __attribute__((ext_vector_type(8))) short short8;
typedef __attribute__((ext_vector_type(4))) float f32x4;

#define NLAY 2
#define NN1 8
#define NN2 8
#define PP 1024
#define DD 768
#define MROWS (NN1*PP)   // 8192
#define BM 256
#define BN 256
#define BK 64
#define NKT (DD/BK)      // 12 K-tiles
#define NCT (MROWS/BN)   // 32 col tiles

// ---------------- normalize rows + convert to bf16 (both inputs fused) ----
__global__ __launch_bounds__(256) void normalize_kernel(
    const float* __restrict__ in0, const float* __restrict__ in1,
    bf16* __restrict__ out0, bf16* __restrict__ out1) {
  int row  = blockIdx.x * 4 + (threadIdx.x >> 6);
  int lane = threadIdx.x & 63;
  const int half = NLAY * MROWS;
  const float* src;
  bf16* dst;
  if (row < half) { src = in0 + (size_t)row * DD;          dst = out0 + (size_t)row * DD; }
  else            { src = in1 + (size_t)(row - half) * DD; dst = out1 + (size_t)(row - half) * DD; }
  float4 v[3];
  float ss = 0.f;
#pragma unroll
  for (int i = 0; i < 3; i++) {
    v[i] = *reinterpret_cast<const float4*>(src + lane * 4 + i * 256);
    ss += v[i].x * v[i].x + v[i].y * v[i].y + v[i].z * v[i].z + v[i].w * v[i].w;
  }
#pragma unroll
  for (int off = 1; off < 64; off <<= 1) ss += __shfl_xor(ss, off);
  float rn = rsqrtf(ss);
#pragma unroll
  for (int i = 0; i < 3; i++) {
    bf16 tmp[4];
    tmp[0] = __float2bfloat16(v[i].x * rn);
    tmp[1] = __float2bfloat16(v[i].y * rn);
    tmp[2] = __float2bfloat16(v[i].z * rn);
    tmp[3] = __float2bfloat16(v[i].w * rn);
    *reinterpret_cast<uint2*>(dst + lane * 4 + i * 256) =
        *reinterpret_cast<const uint2*>(tmp);
  }
}

// ---------------- 256x256 GEMM, 16x16x32 MFMA, 4 phases / 2 K-tiles --------
// 512 threads = 8 waves (wr = wave>>2 row half, wc = wave&3 col stripe).
// Phase = (buf, qm): A frags read fresh (8 ds_read), B frags (8) read at qm0
// and HELD in registers through qm1. 32 MFMAs per phase.
// LDS: As/Bs [2 dbuf][2 half][128*64] bf16 = 128 KiB. Swizzle: 16B slot s of
// row r stored at s^(r&7); global source pre-swizzled, reads apply same XOR
// (16-row x 4-slot-group read pattern -> 2-way bank aliasing = free).

__device__ __forceinline__ short8 ld_frag(const bf16* h, int r, int slot) {
  return *reinterpret_cast<const short8*>(h + r * 64 + (((slot) ^ (r & 7)) << 3));
}

#define STAGE(Gbase, Lds) do {                                                  \
  _Pragma("unroll")                                                             \
  for (int i_ = 0; i_ < 2; i_++) {                                              \
    int u_ = i_ * 512 + t;                                                      \
    int r_ = u_ >> 3, s_ = u_ & 7;                                              \
    int sc_ = ((s_ ^ (r_ & 7)) << 3);                                           \
    __builtin_amdgcn_global_load_lds(                                           \
      (const __attribute__((address_space(1))) void*)((Gbase) + (size_t)r_ * DD + sc_), \
      (__attribute__((address_space(3))) void*)((Lds) + u_ * 8), 16, 0, 0);     \
  } } while (0)

#define VM2 asm volatile("s_waitcnt vmcnt(2)" ::: "memory")
#define VM0 asm volatile("s_waitcnt vmcnt(0)" ::: "memory")

#define LOAD_A(buf, qm)                                                         \
  _Pragma("unroll") for (int m_ = 0; m_ < 4; m_++)                              \
  _Pragma("unroll") for (int ks_ = 0; ks_ < 2; ks_++)                           \
    af_[m_][ks_] = ld_frag(&As[buf][qm][0], wr * 64 + m_ * 16 + rrow, ks_ * 4 + krow);

#define LOAD_B(buf)                                                             \
  _Pragma("unroll") for (int q_ = 0; q_ < 2; q_++)                              \
  _Pragma("unroll") for (int n_ = 0; n_ < 2; n_++)                              \
  _Pragma("unroll") for (int ks_ = 0; ks_ < 2; ks_++)                           \
    bf_[q_][n_][ks_] = ld_frag(&Bs[buf][q_][0], wc * 32 + n_ * 16 + rrow, ks_ * 4 + krow);

#define PHASEQ(buf, qm, LDB, STG, VMC) do {                                     \
  LOAD_A(buf, qm);                                                              \
  LDB;                                                                          \
  STG;                                                                          \
  __builtin_amdgcn_s_barrier();                                                 \
  asm volatile("s_waitcnt lgkmcnt(0)" ::: "memory");                            \
  __builtin_amdgcn_s_setprio(1);                                                \
  _Pragma("unroll") for (int q_ = 0; q_ < 2; q_++)                              \
  _Pragma("unroll") for (int n_ = 0; n_ < 2; n_++)                              \
  _Pragma("unroll") for (int m_ = 0; m_ < 4; m_++)                              \
  _Pragma("unroll") for (int ks_ = 0; ks_ < 2; ks_++)                           \
    acc[(qm) * 4 + m_][q_ * 2 + n_] = __builtin_amdgcn_mfma_f32_16x16x32_bf16(  \
        af_[m_][ks_], bf_[q_][n_][ks_], acc[(qm) * 4 + m_][q_ * 2 + n_], 0, 0, 0); \
  __builtin_amdgcn_s_setprio(0);                                                \
  VMC;                                                                          \
  __builtin_amdgcn_s_barrier();                                                 \
} while (0)

__global__ __launch_bounds__(512, 2) void gemm_max_kernel(
    const bf16* __restrict__ A, const bf16* __restrict__ Bm,
    float* __restrict__ partials) {
  __shared__ bf16 As[2][2][128 * 64];
  __shared__ bf16 Bs[2][2][128 * 64];
  __shared__ float red[4][256];

  // XCD-aware swizzle: xcd = id&7 owns (layer, 8-tiler band); consecutive
  // dispatch rounds within a chunk cover 8 tiler x 4 tilec (~4.7MB in L2).
  const int id  = blockIdx.x;
  const int xcd = id & 7, p = id >> 3;
  const int l     = xcd >> 2;
  const int q     = p & 31, rnd = p >> 5;
  const int tiler = (xcd & 3) * 8 + (q & 7);
  const int tilec = rnd * 4 + (q >> 3);

  const bf16* Ab = A  + ((size_t)l * MROWS + (size_t)tiler * BM) * DD;
  const bf16* Bb = Bm + ((size_t)l * MROWS + (size_t)tilec * BN) * DD;

  const int t    = threadIdx.x;
  const int lane = t & 63;
  const int wave = t >> 6;
  const int wr   = wave >> 2;   // 0..1
  const int wc   = wave & 3;    // 0..3
  const int rrow = lane & 15;
  const int krow = lane >> 4;

  f32x4 acc[8][4];
#pragma unroll
  for (int m = 0; m < 8; m++)
#pragma unroll
    for (int n = 0; n < 4; n++) acc[m][n] = (f32x4){0.f, 0.f, 0.f, 0.f};

  // prologue: tile0 (4 units) -> buf0, As10(tile1) -> buf1
  STAGE(Ab,                      &As[0][0][0]);
  STAGE(Ab + (size_t)128 * DD,   &As[0][1][0]);
  STAGE(Bb,                      &Bs[0][0][0]);
  STAGE(Bb + (size_t)128 * DD,   &Bs[0][1][0]);
  STAGE(Ab + BK,                 &As[1][0][0]);
  VM2;
  __builtin_amdgcn_s_barrier();

  for (int i = 0; i < NKT / 2; i++) {
    const int O = 2 * i + 1, E2 = 2 * i + 2, O2 = 2 * i + 3;
    short8 af_[4][2], bf_[2][2][2];
    // P1: buf0 qm0; stage odd tile's As11, Bs10, Bs11
    PHASEQ(0, 0, LOAD_B(0),
      { STAGE(Ab + (size_t)128 * DD + (size_t)O * BK, &As[1][1][0]);
        STAGE(Bb + (size_t)O * BK,                    &Bs[1][0][0]);
        STAGE(Bb + (size_t)128 * DD + (size_t)O * BK, &Bs[1][1][0]); }, (void)0);
    // P2: buf0 qm1 (B held); stage As00(E+2); counted vmcnt
    PHASEQ(0, 1, (void)0,
      if (E2 < NKT) STAGE(Ab + (size_t)E2 * BK, &As[0][0][0]),
      if (E2 < NKT) { VM2; } else { VM0; });
    // P3: buf1 qm0; stage As01, Bs00, Bs01 (E+2)
    PHASEQ(1, 0, LOAD_B(1),
      if (E2 < NKT) { STAGE(Ab + (size_t)128 * DD + (size_t)E2 * BK, &As[0][1][0]);
                      STAGE(Bb + (size_t)E2 * BK,                    &Bs[0][0][0]);
                      STAGE(Bb + (size_t)128 * DD + (size_t)E2 * BK, &Bs[0][1][0]); }, (void)0);
    // P4: buf1 qm1 (B held); stage As10(O+2); counted vmcnt
    PHASEQ(1, 1, (void)0,
      if (O2 < NKT) STAGE(Ab + (size_t)O2 * BK, &As[1][0][0]),
      if (O2 < NKT) { VM2; });
  }

  // epilogue: per-row max over this block's 256 cols.
  // C/D frag (16x16): col = lane&15, row = (lane>>4)*4 + j
#pragma unroll
  for (int m = 0; m < 8; m++) {
#pragma unroll
    for (int j = 0; j < 4; j++) {
      float v = acc[m][0][j];
      v = fmaxf(v, acc[m][1][j]);
      v = fmaxf(v, acc[m][2][j]);
      v = fmaxf(v, acc[m][3][j]);
#pragma unroll
      for (int off = 1; off < 16; off <<= 1) v = fmaxf(v, __shfl_xor(v, off));
      if (rrow == 0) {
        int row = (m >> 2) * 128 + wr * 64 + (m & 3) * 16 + krow * 4 + j;
        red[wc][row] = v;
      }
    }
  }
  __syncthreads();
  if (t < 256) {
    float v = fmaxf(fmaxf(red[0][t], red[1][t]), fmaxf(red[2][t], red[3][t]));
    partials[((size_t)l * MROWS + (size_t)tiler * BM + t) * NCT + tilec] = v;
  }
}

// ---------------- reduce: maxdot -> sp -> scores + spatch ------------------
__global__ __launch_bounds__(1024) void reduce_kernel(
    const float* __restrict__ partials, const float* __restrict__ mask,
    float* __restrict__ scores, float* __restrict__ spatch) {
  const int n1 = blockIdx.x;
  const int p  = threadIdx.x;
  const int row = n1 * PP + p;
  const float mk = mask[row];

  float sp[16];
  float ssum = 0.f;
#pragma unroll
  for (int l = 0; l < NLAY; l++) {
    const float* pr = partials + ((size_t)l * MROWS + row) * NCT;
#pragma unroll
    for (int n2 = 0; n2 < NN2; n2++) {
      float md = pr[n2 * 4];
#pragma unroll
      for (int tt = 1; tt < 4; tt++) md = fmaxf(md, pr[n2 * 4 + tt]);
      float d2 = fmaxf(2.f - 2.f * md, 1e-12f);
      float s  = 0.5f * sqrtf(d2) * mk;
      sp[l * 8 + n2] = s;
      ssum += s;
    }
  }
  spatch[row] = ssum * (1.f / 16.f);

  __shared__ float wred[16][16];
  __shared__ float sres[16];
  const int lane = p & 63;
  const int wave = p >> 6;
#pragma unroll
  for (int v = 0; v < 16; v++) {
    float x = sp[v];
#pragma unroll
    for (int off = 1; off < 64; off <<= 1) x = fmaxf(x, __shfl_xor(x, off));
    if (lane == 0) wred[wave][v] = x;
  }
  __syncthreads();
  if (p < 16) {
    float x = wred[0][p];
#pragma unroll
    for (int w = 1; w < 16; w++) x = fmaxf(x, wred[w][p]);
    sres[p] = x;
  }
  __syncthreads();
  if (p == 0) {
    float s = 0.f;
#pragma unroll
    for (int v = 0; v < 16; v++) s += sres[v];
    scores[n1] = s * (1.f / 16.f);
  }
}

// ---------------- bilinear 16x upsample [8,32,32] -> [8,512,512] -----------
__global__ __launch_bounds__(256) void upsample_kernel(
    const float* __restrict__ spatch, float* __restrict__ out) {
  int idx = blockIdx.x * 256 + threadIdx.x;
  if (idx >= NN1 * 512 * 512) return;
  int x = idx & 511;
  int y = (idx >> 9) & 511;
  int n = idx >> 18;
  float sx = (x + 0.5f) * 0.0625f - 0.5f;
  float sy = (y + 0.5f) * 0.0625f - 0.5f;
  int x0 = (int)floorf(sx); float wx = sx - (float)x0;
  int y0 = (int)floorf(sy); float wy = sy - (float)y0;
  int x1 = min(x0 + 1, 31); x0 = max(x0, 0);
  int y1 = min(y0 + 1, 31); y0 = max(y0, 0);
  const float* s = spatch + n * PP;
  float v00 = s[y0 * 32 + x0], v01 = s[y0 * 32 + x1];
  float v10 = s[y1 * 32 + x0], v11 = s[y1 * 32 + x1];
  float v = (1.f - wy) * ((1.f - wx) * v00 + wx * v01) +
            wy * ((1.f - wx) * v10 + wx * v11);
  out[idx] = v;
}

extern "C" void kernel_launch(void* const* d_in, const int* in_sizes, int n_in,
                              void* d_out, int out_size, void* d_ws, size_t ws_size,
                              hipStream_t stream) {
  const float* feats  = (const float*)d_in[0];
  const float* nfeats = (const float*)d_in[1];
  const float* mask   = (const float*)d_in[2];
  float* out = (float*)d_out;

  bf16* Abf = (bf16*)d_ws;                                     // 2*8192*768 bf16
  bf16* Bbf = Abf + (size_t)NLAY * MROWS * DD;                 // same size
  float* partials = (float*)(Bbf + (size_t)NLAY * MROWS * DD); // [2][8192][32] f32
  float* spatch   = partials + (size_t)NLAY * MROWS * NCT;     // [8][1024] f32

  normalize_kernel<<<(2 * NLAY * MROWS) / 4, 256, 0, stream>>>(feats, nfeats, Abf, Bbf);

  gemm_max_kernel<<<NCT * (MROWS / BM) * NLAY, 512, 0, stream>>>(Abf, Bbf, partials);

  reduce_kernel<<<NN1, 1024, 0, stream>>>(partials, mask, out, spatch);

  upsample_kernel<<<(NN1 * 512 * 512) / 256, 256, 0, stream>>>(spatch, out + 8);
}